// Round 2
// baseline (8812.213 us; speedup 1.0000x reference)
//
#include <hip/hip_runtime.h>
#include <math.h>

#define Bc 2
#define Tc 2048
#define Dc 1024
#define Hc 16
#define HDc 64
#define Mc (Bc * Tc)   // 4096 rows

// ---------------- LayerNorm: one block per row, 256 threads, float4 ----------------
__global__ __launch_bounds__(256) void ln_kernel(const float* __restrict__ x,
                                                 const float* __restrict__ g,
                                                 const float* __restrict__ be,
                                                 float* __restrict__ out) {
  const int row = blockIdx.x;
  const int t = threadIdx.x;
  const float4* xp = (const float4*)(x + (size_t)row * Dc);
  float4 v = xp[t];
  float s  = v.x + v.y + v.z + v.w;
  float s2 = v.x * v.x + v.y * v.y + v.z * v.z + v.w * v.w;
#pragma unroll
  for (int off = 32; off; off >>= 1) {
    s  += __shfl_down(s, off);
    s2 += __shfl_down(s2, off);
  }
  __shared__ float rs[4], rs2[4];
  if ((t & 63) == 0) { rs[t >> 6] = s; rs2[t >> 6] = s2; }
  __syncthreads();
  float S  = rs[0] + rs[1] + rs[2] + rs[3];
  float S2 = rs2[0] + rs2[1] + rs2[2] + rs2[3];
  float mean = S * (1.0f / Dc);
  float var  = S2 * (1.0f / Dc) - mean * mean;
  float rstd = rsqrtf(var + 1e-5f);
  float4 gv = ((const float4*)g)[t];
  float4 bv = ((const float4*)be)[t];
  float4 o;
  o.x = (v.x - mean) * rstd * gv.x + bv.x;
  o.y = (v.y - mean) * rstd * gv.y + bv.y;
  o.z = (v.z - mean) * rstd * gv.z + bv.z;
  o.w = (v.w - mean) * rstd * gv.w + bv.w;
  ((float4*)(out + (size_t)row * Dc))[t] = o;
}

// ---------------- fp32 GEMM: C[M,N] = A[M,K] @ W[K,N], fused epilogue ----------------
// flags: 1 = +bias, 2 = exact GELU, 4 = +resid
#define BM 128
#define BN 128
#define BK 16
#define PAD 4

__global__ __launch_bounds__(256) void gemm_kernel(const float* __restrict__ A,
                                                   const float* __restrict__ W,
                                                   const float* __restrict__ bias,
                                                   const float* __restrict__ resid,
                                                   float* __restrict__ C,
                                                   int M, int N, int K, int flags) {
  __shared__ float As[BK][BM + PAD];
  __shared__ float Bs[BK][BN + PAD];
  const int t = threadIdx.x;
  const int tx = t & 15, ty = t >> 4;
  const int row0 = blockIdx.y * BM, col0 = blockIdx.x * BN;
  float acc[8][8] = {};

  for (int k0 = 0; k0 < K; k0 += BK) {
#pragma unroll
    for (int i = 0; i < 8; i++) {       // A tile: 128x16, kk fastest for coalescing
      int l = t + 256 * i;
      int r = l >> 4, kk = l & 15;
      As[kk][r] = A[(size_t)(row0 + r) * K + k0 + kk];
    }
#pragma unroll
    for (int i = 0; i < 8; i++) {       // B tile: 16x128, col fastest (coalesced)
      int l = t + 256 * i;
      int kk = l >> 7, c = l & 127;
      Bs[kk][c] = W[(size_t)(k0 + kk) * N + col0 + c];
    }
    __syncthreads();
#pragma unroll
    for (int kk = 0; kk < BK; kk++) {
      float4 a0 = *(const float4*)&As[kk][ty * 8];
      float4 a1 = *(const float4*)&As[kk][ty * 8 + 4];
      float4 b0 = *(const float4*)&Bs[kk][tx * 8];
      float4 b1 = *(const float4*)&Bs[kk][tx * 8 + 4];
      float a[8] = {a0.x, a0.y, a0.z, a0.w, a1.x, a1.y, a1.z, a1.w};
      float b[8] = {b0.x, b0.y, b0.z, b0.w, b1.x, b1.y, b1.z, b1.w};
#pragma unroll
      for (int i = 0; i < 8; i++)
#pragma unroll
        for (int j = 0; j < 8; j++)
          acc[i][j] = fmaf(a[i], b[j], acc[i][j]);
    }
    __syncthreads();
  }

#pragma unroll
  for (int i = 0; i < 8; i++) {
    int r = row0 + ty * 8 + i;
#pragma unroll
    for (int j = 0; j < 8; j++) {
      int c = col0 + tx * 8 + j;
      float v = acc[i][j];
      if (flags & 1) v += bias[c];
      if (flags & 2) v = 0.5f * v * (1.0f + erff(v * 0.70710678118654752f));
      if (flags & 4) v += resid[(size_t)r * N + c];
      C[(size_t)r * N + c] = v;
    }
  }
}

// ---------------- Attention: one block per (b,h,q) row, full score row in LDS -------
__global__ __launch_bounds__(256) void attn_kernel(const float* __restrict__ qkv,
                                                   float* __restrict__ out) {
  __shared__ float sS[Tc];     // 8 KB score row
  __shared__ float sQ[HDc];
  __shared__ float red[8];
  __shared__ float sP[256];

  const int bid = blockIdx.x;
  const int q = bid & (Tc - 1);
  const int h = (bid >> 11) & (Hc - 1);
  const int b = bid >> 15;
  const int t = threadIdx.x;

  const size_t base = (size_t)(b * Tc) * (3 * Dc);
  const size_t qoff = base + (size_t)q * (3 * Dc) + h * HDc;          // s=0
  if (t < HDc) sQ[t] = qkv[qoff + t];
  __syncthreads();

  const float4* sQ4 = (const float4*)sQ;
  const float scale = 0.125f;  // 1/sqrt(64)
  for (int k = t; k < Tc; k += 256) {
    const float4* Kp = (const float4*)(qkv + base + (size_t)k * (3 * Dc) + Dc + h * HDc);
    float dot = 0.0f;
#pragma unroll
    for (int i = 0; i < 16; i++) {
      float4 kv = Kp[i];
      float4 qv = sQ4[i];
      dot += qv.x * kv.x + qv.y * kv.y + qv.z * kv.z + qv.w * kv.w;
    }
    sS[k] = dot * scale;
  }
  __syncthreads();

  // softmax: max
  float mx = -1e30f;
  for (int k = t; k < Tc; k += 256) mx = fmaxf(mx, sS[k]);
#pragma unroll
  for (int off = 32; off; off >>= 1) mx = fmaxf(mx, __shfl_down(mx, off));
  if ((t & 63) == 0) red[t >> 6] = mx;
  __syncthreads();
  if (t == 0) red[4] = fmaxf(fmaxf(red[0], red[1]), fmaxf(red[2], red[3]));
  __syncthreads();
  mx = red[4];

  // exp + sum
  float sum = 0.0f;
  for (int k = t; k < Tc; k += 256) {
    float e = __expf(sS[k] - mx);
    sS[k] = e;
    sum += e;
  }
#pragma unroll
  for (int off = 32; off; off >>= 1) sum += __shfl_down(sum, off);
  if ((t & 63) == 0) red[t >> 6] = sum;
  __syncthreads();
  if (t == 0) red[5] = red[0] + red[1] + red[2] + red[3];
  __syncthreads();
  const float inv = 1.0f / red[5];

  // PV: thread t handles d = t&63, k-chunk = t>>6
  const int d = t & 63, chunk = t >> 6;
  float acc = 0.0f;
  const float* Vp = qkv + base + 2 * Dc + h * HDc + d;
  for (int k = chunk * (Tc / 4); k < (chunk + 1) * (Tc / 4); k++) {
    acc += sS[k] * Vp[(size_t)k * (3 * Dc)];
  }
  sP[t] = acc;
  __syncthreads();
  if (t < HDc) {
    float v = (sP[t] + sP[t + 64] + sP[t + 128] + sP[t + 192]) * inv;
    out[(size_t)(b * Tc + q) * Dc + h * HDc + t] = v;
  }
}

extern "C" void kernel_launch(void* const* d_in, const int* in_sizes, int n_in,
                              void* d_out, int out_size, void* d_ws, size_t ws_size,
                              hipStream_t stream) {
  const float* x     = (const float*)d_in[0];
  const float* w_qkv = (const float*)d_in[1];
  const float* w_out = (const float*)d_in[2];
  const float* w_ff1 = (const float*)d_in[3];
  const float* b_ff1 = (const float*)d_in[4];
  const float* w_ff2 = (const float*)d_in[5];
  const float* b_ff2 = (const float*)d_in[6];
  const float* g1    = (const float*)d_in[7];
  const float* be1   = (const float*)d_in[8];
  const float* g2    = (const float*)d_in[9];
  const float* be2   = (const float*)d_in[10];

  char* ws = (char*)d_ws;
  float* qkv_h  = (float*)ws;                          // 64 MB: qkv (48 MB) then h (64 MB)
  float* attn_o = (float*)(ws + ((size_t)64 << 20));   // 16 MB
  float* x2     = (float*)(ws + ((size_t)80 << 20));   // 16 MB
  float* xn     = (float*)d_out;                       // LN output scratch (overwritten at end)

  dim3 blk(256);

  // xn = LN(x, g1, be1)
  ln_kernel<<<Mc, blk, 0, stream>>>(x, g1, be1, xn);
  // qkv = xn @ w_qkv
  gemm_kernel<<<dim3(3 * Dc / BN, Mc / BM), blk, 0, stream>>>(xn, w_qkv, nullptr, nullptr,
                                                              qkv_h, Mc, 3 * Dc, Dc, 0);
  // attention
  attn_kernel<<<Bc * Hc * Tc, blk, 0, stream>>>(qkv_h, attn_o);
  // x2 = x + attn_o @ w_out
  gemm_kernel<<<dim3(Dc / BN, Mc / BM), blk, 0, stream>>>(attn_o, w_out, nullptr, x,
                                                          x2, Mc, Dc, Dc, 4);
  // xn = LN(x2, g2, be2)
  ln_kernel<<<Mc, blk, 0, stream>>>(x2, g2, be2, xn);
  // h = gelu(xn @ w_ff1 + b_ff1)
  gemm_kernel<<<dim3(4 * Dc / BN, Mc / BM), blk, 0, stream>>>(xn, w_ff1, b_ff1, nullptr,
                                                              qkv_h, Mc, 4 * Dc, Dc, 1 | 2);
  // out = x2 + h @ w_ff2 + b_ff2
  gemm_kernel<<<dim3(Dc / BN, Mc / BM), blk, 0, stream>>>(qkv_h, w_ff2, b_ff2, x2,
                                                          (float*)d_out, Mc, Dc, 4 * Dc, 1 | 4);
}

// Round 3
// 643.844 us; speedup vs baseline: 13.6869x; 13.6869x over previous
//
#include <hip/hip_runtime.h>
#include <math.h>

#define Bc 2
#define Tc 2048
#define Dc 1024
#define Hc 16
#define HDc 64
#define Mc (Bc * Tc)   // 4096 rows

typedef __attribute__((ext_vector_type(4))) float f32x4;
typedef __attribute__((ext_vector_type(8))) short bf16x8;

__device__ __forceinline__ unsigned short f2bf(float f) {
  unsigned int u = __float_as_uint(f);
  u += 0x7fff + ((u >> 16) & 1);          // RNE
  return (unsigned short)(u >> 16);
}

__device__ __forceinline__ void gload16(const void* g, void* l) {
  __builtin_amdgcn_global_load_lds((const __attribute__((address_space(1))) unsigned int*)g,
                                   (__attribute__((address_space(3))) unsigned int*)l, 16, 0, 0);
}

// ---------- weight convert+transpose: W[K][N] f32 -> Wt[N][K] bf16 ----------
__global__ __launch_bounds__(256) void wconv_kernel(const float* __restrict__ W,
                                                    unsigned short* __restrict__ Wt,
                                                    int K, int N) {
  __shared__ float tile[64][65];
  const int t = threadIdx.x;
  const int kt = blockIdx.y * 64, nt = blockIdx.x * 64;
#pragma unroll
  for (int p = 0; p < 4; p++) {
    int kr = p * 16 + (t >> 4);
    int nc = (t & 15) * 4;
    float4 v = *(const float4*)&W[(size_t)(kt + kr) * N + nt + nc];
    tile[kr][nc] = v.x; tile[kr][nc + 1] = v.y; tile[kr][nc + 2] = v.z; tile[kr][nc + 3] = v.w;
  }
  __syncthreads();
  const int nr = t >> 2, kc = (t & 3) * 16;
  unsigned int u[8];
#pragma unroll
  for (int i = 0; i < 8; i++)
    u[i] = (unsigned int)f2bf(tile[kc + 2 * i][nr]) | ((unsigned int)f2bf(tile[kc + 2 * i + 1][nr]) << 16);
  uint4 w0; w0.x = u[0]; w0.y = u[1]; w0.z = u[2]; w0.w = u[3];
  uint4 w1; w1.x = u[4]; w1.y = u[5]; w1.z = u[6]; w1.w = u[7];
  *(uint4*)&Wt[(size_t)(nt + nr) * K + kt + kc] = w0;
  *(uint4*)&Wt[(size_t)(nt + nr) * K + kt + kc + 8] = w1;
}

// ---------- LayerNorm: fp32 in, bf16 out ----------
__global__ __launch_bounds__(256) void ln_kernel(const float* __restrict__ x,
                                                 const float* __restrict__ g,
                                                 const float* __restrict__ be,
                                                 unsigned short* __restrict__ out) {
  const int row = blockIdx.x;
  const int t = threadIdx.x;
  const float4* xp = (const float4*)(x + (size_t)row * Dc);
  float4 v = xp[t];
  float s = v.x + v.y + v.z + v.w;
  float s2 = v.x * v.x + v.y * v.y + v.z * v.z + v.w * v.w;
#pragma unroll
  for (int off = 32; off; off >>= 1) {
    s += __shfl_down(s, off);
    s2 += __shfl_down(s2, off);
  }
  __shared__ float rs[4], rs2[4];
  if ((t & 63) == 0) { rs[t >> 6] = s; rs2[t >> 6] = s2; }
  __syncthreads();
  float S = rs[0] + rs[1] + rs[2] + rs[3];
  float S2 = rs2[0] + rs2[1] + rs2[2] + rs2[3];
  float mean = S * (1.0f / Dc);
  float var = S2 * (1.0f / Dc) - mean * mean;
  float rstd = rsqrtf(var + 1e-5f);
  float4 gv = ((const float4*)g)[t];
  float4 bv = ((const float4*)be)[t];
  float o0 = (v.x - mean) * rstd * gv.x + bv.x;
  float o1 = (v.y - mean) * rstd * gv.y + bv.y;
  float o2 = (v.z - mean) * rstd * gv.z + bv.z;
  float o3 = (v.w - mean) * rstd * gv.w + bv.w;
  uint2 pk;
  pk.x = (unsigned int)f2bf(o0) | ((unsigned int)f2bf(o1) << 16);
  pk.y = (unsigned int)f2bf(o2) | ((unsigned int)f2bf(o3) << 16);
  *(uint2*)(out + (size_t)row * Dc + t * 4) = pk;
}

// ---------- bf16 MFMA GEMM: C[M,N] = A[M,K] @ Wt[N,K]^T, fused epilogue ----------
// flags: 1=+bias, 2=exact GELU, 4=+resid(fp32), 8=write bf16 to aux, 16=qkv split write
#define GBM 128
#define GBN 128
#define GBK 32

__global__ __launch_bounds__(256) void gemm_bf16(const unsigned short* __restrict__ A,
                                                 const unsigned short* __restrict__ Wt,
                                                 const float* __restrict__ bias,
                                                 const float* __restrict__ resid,
                                                 float* __restrict__ C,
                                                 unsigned short* __restrict__ aux,
                                                 int M, int N, int K, int flags) {
  __shared__ alignas(16) unsigned short As[GBM][GBK];   // 8 KB, row stride 64 B
  __shared__ alignas(16) unsigned short Bs[GBN][GBK];   // 8 KB (n-major)
  const int t = threadIdx.x;
  const int lane = t & 63, wave = t >> 6;
  const int wr = wave >> 1, wc = wave & 1;
  const int c = lane & 15, g = lane >> 4;
  const int row0 = blockIdx.y * GBM, col0 = blockIdx.x * GBN;

  f32x4 acc[4][4];
#pragma unroll
  for (int m = 0; m < 4; m++)
#pragma unroll
    for (int n = 0; n < 4; n++) acc[m][n] = (f32x4){0.f, 0.f, 0.f, 0.f};

  char* AsB = (char*)&As[0][0];
  char* BsB = (char*)&Bs[0][0];
  const int l0 = t, l1 = t + 256;
  const int lds0 = wave * 1024, lds1 = wave * 1024 + 4096;   // wave-uniform LDS bases

  for (int k0 = 0; k0 < K; k0 += GBK) {
    gload16(A + (size_t)(row0 + (l0 >> 2)) * K + k0 + (l0 & 3) * 8, AsB + lds0);
    gload16(A + (size_t)(row0 + (l1 >> 2)) * K + k0 + (l1 & 3) * 8, AsB + lds1);
    gload16(Wt + (size_t)(col0 + (l0 >> 2)) * K + k0 + (l0 & 3) * 8, BsB + lds0);
    gload16(Wt + (size_t)(col0 + (l1 >> 2)) * K + k0 + (l1 & 3) * 8, BsB + lds1);
    __syncthreads();
    bf16x8 af[4], bfv[4];
#pragma unroll
    for (int m = 0; m < 4; m++) af[m] = *(const bf16x8*)(AsB + (wr * 64 + m * 16 + c) * 64 + g * 16);
#pragma unroll
    for (int n = 0; n < 4; n++) bfv[n] = *(const bf16x8*)(BsB + (wc * 64 + n * 16 + c) * 64 + g * 16);
#pragma unroll
    for (int m = 0; m < 4; m++)
#pragma unroll
      for (int n = 0; n < 4; n++)
        acc[m][n] = __builtin_amdgcn_mfma_f32_16x16x32_bf16(af[m], bfv[n], acc[m][n], 0, 0, 0);
    __syncthreads();
  }

#pragma unroll
  for (int m = 0; m < 4; m++) {
    const int row = row0 + wr * 64 + m * 16 + g * 4;
#pragma unroll
    for (int n = 0; n < 4; n++) {
      const int col = col0 + wc * 64 + n * 16 + c;
      const float bi = (flags & 1) ? bias[col] : 0.0f;
#pragma unroll
      for (int r = 0; r < 4; r++) {
        float v = acc[m][n][r] + bi;
        if (flags & 2) v = 0.5f * v * (1.0f + erff(v * 0.70710678118654752f));
        if (flags & 4) v += resid[(size_t)(row + r) * N + col];
        if (flags & 16) {
          // qkv split: Q at aux, K at aux+4M, V^T at aux+8M (bf16 elements)
          int rr = row + r;
          int b = rr >> 11, tt = rr & 2047;
          int s = col >> 10, wcol = col & 1023;
          int h = wcol >> 6, f = wcol & 63;
          int bh = b * Hc + h;
          unsigned short bv = f2bf(v);
          if (s == 0)      aux[(size_t)bh * Tc * HDc + (size_t)tt * HDc + f] = bv;
          else if (s == 1) aux[4194304 + (size_t)bh * Tc * HDc + (size_t)tt * HDc + f] = bv;
          else             aux[8388608 + ((size_t)bh * HDc + f) * Tc + tt] = bv;
        } else if (flags & 8) {
          aux[(size_t)(row + r) * N + col] = f2bf(v);
        } else {
          C[(size_t)(row + r) * N + col] = v;
        }
      }
    }
  }
}

// ---------- MFMA flash attention ----------
// Qb,Kb: [32 bh][2048][64] bf16 ; Vt: [32 bh][64][2048] bf16 ; Ob: [B][T][D] bf16
__global__ __launch_bounds__(256) void fattn(const unsigned short* __restrict__ Qb,
                                             const unsigned short* __restrict__ Kb,
                                             const unsigned short* __restrict__ Vt,
                                             unsigned short* __restrict__ Ob) {
  __shared__ alignas(16) unsigned short P[4][16][32];   // per-wave P tile
  const int t = threadIdx.x, wave = t >> 6, lane = t & 63;
  const int c = lane & 15, g = lane >> 4;
  const int bid = blockIdx.x;
  const int bh = bid >> 5, qt = bid & 31;
  const int q0 = qt * 64 + wave * 16;

  const unsigned short* Qp = Qb + ((size_t)bh * Tc + q0) * HDc;
  const unsigned short* Kp = Kb + (size_t)bh * Tc * HDc;
  const unsigned short* Vp = Vt + (size_t)bh * HDc * Tc;

  const bf16x8 qf0 = *(const bf16x8*)(Qp + c * HDc + g * 8);
  const bf16x8 qf1 = *(const bf16x8*)(Qp + c * HDc + 32 + g * 8);

  const f32x4 z = {0.f, 0.f, 0.f, 0.f};
  f32x4 o0 = z, o1 = z, o2 = z, o3 = z;
  float mrow[4] = {-1e30f, -1e30f, -1e30f, -1e30f};
  float lrow[4] = {0.f, 0.f, 0.f, 0.f};
  const float scale = 0.125f;   // 1/sqrt(64)

  for (int kt = 0; kt < Tc; kt += 32) {
    const bf16x8 k00 = *(const bf16x8*)(Kp + (size_t)(kt + c) * HDc + g * 8);
    const bf16x8 k01 = *(const bf16x8*)(Kp + (size_t)(kt + c) * HDc + 32 + g * 8);
    const bf16x8 k10 = *(const bf16x8*)(Kp + (size_t)(kt + 16 + c) * HDc + g * 8);
    const bf16x8 k11 = *(const bf16x8*)(Kp + (size_t)(kt + 16 + c) * HDc + 32 + g * 8);
    f32x4 s0 = __builtin_amdgcn_mfma_f32_16x16x32_bf16(qf0, k00, z, 0, 0, 0);
    s0 = __builtin_amdgcn_mfma_f32_16x16x32_bf16(qf1, k01, s0, 0, 0, 0);
    f32x4 s1 = __builtin_amdgcn_mfma_f32_16x16x32_bf16(qf0, k10, z, 0, 0, 0);
    s1 = __builtin_amdgcn_mfma_f32_16x16x32_bf16(qf1, k11, s1, 0, 0, 0);

    float ef[4];
#pragma unroll
    for (int r = 0; r < 4; r++) {
      float a = s0[r] * scale, b = s1[r] * scale;
      float rm = fmaxf(a, b);
      rm = fmaxf(rm, __shfl_xor(rm, 1));
      rm = fmaxf(rm, __shfl_xor(rm, 2));
      rm = fmaxf(rm, __shfl_xor(rm, 4));
      rm = fmaxf(rm, __shfl_xor(rm, 8));
      float nm = fmaxf(mrow[r], rm);
      ef[r] = __expf(mrow[r] - nm);
      mrow[r] = nm;
      float p0 = __expf(a - nm), p1 = __expf(b - nm);
      lrow[r] = lrow[r] * ef[r] + p0 + p1;
      P[wave][g * 4 + r][c] = f2bf(p0);
      P[wave][g * 4 + r][16 + c] = f2bf(p1);
    }
#pragma unroll
    for (int r = 0; r < 4; r++) { o0[r] *= ef[r]; o1[r] *= ef[r]; o2[r] *= ef[r]; o3[r] *= ef[r]; }

    const bf16x8 pf = *(const bf16x8*)&P[wave][c][g * 8];
    const bf16x8 v0 = *(const bf16x8*)(Vp + (size_t)(c) * Tc + kt + g * 8);
    const bf16x8 v1 = *(const bf16x8*)(Vp + (size_t)(16 + c) * Tc + kt + g * 8);
    const bf16x8 v2 = *(const bf16x8*)(Vp + (size_t)(32 + c) * Tc + kt + g * 8);
    const bf16x8 v3 = *(const bf16x8*)(Vp + (size_t)(48 + c) * Tc + kt + g * 8);
    o0 = __builtin_amdgcn_mfma_f32_16x16x32_bf16(pf, v0, o0, 0, 0, 0);
    o1 = __builtin_amdgcn_mfma_f32_16x16x32_bf16(pf, v1, o1, 0, 0, 0);
    o2 = __builtin_amdgcn_mfma_f32_16x16x32_bf16(pf, v2, o2, 0, 0, 0);
    o3 = __builtin_amdgcn_mfma_f32_16x16x32_bf16(pf, v3, o3, 0, 0, 0);
  }

#pragma unroll
  for (int r = 0; r < 4; r++) {
    float L = lrow[r];
    L += __shfl_xor(L, 1); L += __shfl_xor(L, 2); L += __shfl_xor(L, 4); L += __shfl_xor(L, 8);
    lrow[r] = 1.0f / L;
  }
  const int b = bh >> 4, h = bh & 15;
#pragma unroll
  for (int r = 0; r < 4; r++) {
    size_t rowoff = ((size_t)b * Tc + q0 + g * 4 + r) * Dc + h * HDc + c;
    Ob[rowoff + 0]  = f2bf(o0[r] * lrow[r]);
    Ob[rowoff + 16] = f2bf(o1[r] * lrow[r]);
    Ob[rowoff + 32] = f2bf(o2[r] * lrow[r]);
    Ob[rowoff + 48] = f2bf(o3[r] * lrow[r]);
  }
}

extern "C" void kernel_launch(void* const* d_in, const int* in_sizes, int n_in,
                              void* d_out, int out_size, void* d_ws, size_t ws_size,
                              hipStream_t stream) {
  const float* x     = (const float*)d_in[0];
  const float* w_qkv = (const float*)d_in[1];
  const float* w_out = (const float*)d_in[2];
  const float* w_ff1 = (const float*)d_in[3];
  const float* b_ff1 = (const float*)d_in[4];
  const float* w_ff2 = (const float*)d_in[5];
  const float* b_ff2 = (const float*)d_in[6];
  const float* g1    = (const float*)d_in[7];
  const float* be1   = (const float*)d_in[8];
  const float* g2    = (const float*)d_in[9];
  const float* be2   = (const float*)d_in[10];

  char* ws = (char*)d_ws;
  unsigned short* qkvb  = (unsigned short*)ws;                          // Q|K|Vt bf16, 24 MB [0,24)
  unsigned short* xn    = (unsigned short*)(ws + ((size_t)24 << 20));   // 8 MB  [24,32)
  unsigned short* Ob    = (unsigned short*)(ws + ((size_t)32 << 20));   // 8 MB  [32,40)
  unsigned short* hbuf  = (unsigned short*)(ws + ((size_t)40 << 20));   // 32 MB [40,72)
  unsigned short* wqkvT = (unsigned short*)(ws + ((size_t)72 << 20));   // 6 MB
  unsigned short* woutT = (unsigned short*)(ws + ((size_t)78 << 20));   // 2 MB
  unsigned short* wff1T = (unsigned short*)(ws + ((size_t)80 << 20));   // 8 MB
  unsigned short* wff2T = (unsigned short*)(ws + ((size_t)88 << 20));   // 8 MB -> 96 MB total
  float* x2 = (float*)d_out;   // fp32 residual scratch, overwritten by ff2 at the end

  dim3 blk(256);
  // weight transposes (fp32 -> bf16 [N][K])
  wconv_kernel<<<dim3(48, 16), blk, 0, stream>>>(w_qkv, wqkvT, Dc, 3 * Dc);
  wconv_kernel<<<dim3(16, 16), blk, 0, stream>>>(w_out, woutT, Dc, Dc);
  wconv_kernel<<<dim3(64, 16), blk, 0, stream>>>(w_ff1, wff1T, Dc, 4 * Dc);
  wconv_kernel<<<dim3(16, 64), blk, 0, stream>>>(w_ff2, wff2T, 4 * Dc, Dc);

  // xn = LN(x) in bf16
  ln_kernel<<<Mc, blk, 0, stream>>>(x, g1, be1, xn);
  // qkv GEMM with split Q/K/V^T bf16 epilogue
  gemm_bf16<<<dim3(24, 32), blk, 0, stream>>>(xn, wqkvT, nullptr, nullptr, nullptr, qkvb,
                                              Mc, 3 * Dc, Dc, 16);
  // flash attention
  fattn<<<dim3(1024), blk, 0, stream>>>(qkvb, qkvb + 4194304, qkvb + 8388608, Ob);
  // x2 = x + attn @ w_out   (fp32 into d_out)
  gemm_bf16<<<dim3(8, 32), blk, 0, stream>>>(Ob, woutT, nullptr, x, x2, nullptr,
                                             Mc, Dc, Dc, 4);
  // xn = LN(x2) in bf16
  ln_kernel<<<Mc, blk, 0, stream>>>(x2, g2, be2, xn);
  // h = gelu(xn @ w_ff1 + b1) in bf16
  gemm_bf16<<<dim3(32, 32), blk, 0, stream>>>(xn, wff1T, b_ff1, nullptr, nullptr, hbuf,
                                              Mc, 4 * Dc, Dc, 1 | 2 | 8);
  // out = x2 + h @ w_ff2 + b2  (fp32)
  gemm_bf16<<<dim3(8, 32), blk, 0, stream>>>(hbuf, wff2T, b_ff2, x2, (float*)d_out, nullptr,
                                             Mc, Dc, 4 * Dc, 1 | 4);
}

// Round 4
// 640.919 us; speedup vs baseline: 13.7493x; 1.0046x over previous
//
#include <hip/hip_runtime.h>
#include <math.h>

#define Bc 2
#define Tc 2048
#define Dc 1024
#define Hc 16
#define HDc 64
#define Mc (Bc * Tc)   // 4096 rows

typedef __attribute__((ext_vector_type(4))) float f32x4;
typedef __attribute__((ext_vector_type(8))) short bf16x8;

__device__ __forceinline__ unsigned short f2bf(float f) {
  unsigned int u = __float_as_uint(f);
  u += 0x7fff + ((u >> 16) & 1);          // RNE
  return (unsigned short)(u >> 16);
}

__device__ __forceinline__ void gload16(const void* g, void* l) {
  __builtin_amdgcn_global_load_lds((const __attribute__((address_space(1))) unsigned int*)g,
                                   (__attribute__((address_space(3))) unsigned int*)l, 16, 0, 0);
}

// ---------- weight convert+transpose: W[K][N] f32 -> Wt[N][K] bf16 ----------
__global__ __launch_bounds__(256) void wconv_kernel(const float* __restrict__ W,
                                                    unsigned short* __restrict__ Wt,
                                                    int K, int N) {
  __shared__ float tile[64][65];
  const int t = threadIdx.x;
  const int kt = blockIdx.y * 64, nt = blockIdx.x * 64;
#pragma unroll
  for (int p = 0; p < 4; p++) {
    int kr = p * 16 + (t >> 4);
    int nc = (t & 15) * 4;
    float4 v = *(const float4*)&W[(size_t)(kt + kr) * N + nt + nc];
    tile[kr][nc] = v.x; tile[kr][nc + 1] = v.y; tile[kr][nc + 2] = v.z; tile[kr][nc + 3] = v.w;
  }
  __syncthreads();
  const int nr = t >> 2, kc = (t & 3) * 16;
  unsigned int u[8];
#pragma unroll
  for (int i = 0; i < 8; i++)
    u[i] = (unsigned int)f2bf(tile[kc + 2 * i][nr]) | ((unsigned int)f2bf(tile[kc + 2 * i + 1][nr]) << 16);
  uint4 w0; w0.x = u[0]; w0.y = u[1]; w0.z = u[2]; w0.w = u[3];
  uint4 w1; w1.x = u[4]; w1.y = u[5]; w1.z = u[6]; w1.w = u[7];
  *(uint4*)&Wt[(size_t)(nt + nr) * K + kt + kc] = w0;
  *(uint4*)&Wt[(size_t)(nt + nr) * K + kt + kc + 8] = w1;
}

// ---------- LayerNorm: fp32 in, bf16 out ----------
__global__ __launch_bounds__(256) void ln_kernel(const float* __restrict__ x,
                                                 const float* __restrict__ g,
                                                 const float* __restrict__ be,
                                                 unsigned short* __restrict__ out) {
  const int row = blockIdx.x;
  const int t = threadIdx.x;
  const float4* xp = (const float4*)(x + (size_t)row * Dc);
  float4 v = xp[t];
  float s = v.x + v.y + v.z + v.w;
  float s2 = v.x * v.x + v.y * v.y + v.z * v.z + v.w * v.w;
#pragma unroll
  for (int off = 32; off; off >>= 1) {
    s += __shfl_down(s, off);
    s2 += __shfl_down(s2, off);
  }
  __shared__ float rs[4], rs2[4];
  if ((t & 63) == 0) { rs[t >> 6] = s; rs2[t >> 6] = s2; }
  __syncthreads();
  float S = rs[0] + rs[1] + rs[2] + rs[3];
  float S2 = rs2[0] + rs2[1] + rs2[2] + rs2[3];
  float mean = S * (1.0f / Dc);
  float var = S2 * (1.0f / Dc) - mean * mean;
  float rstd = rsqrtf(var + 1e-5f);
  float4 gv = ((const float4*)g)[t];
  float4 bv = ((const float4*)be)[t];
  float o0 = (v.x - mean) * rstd * gv.x + bv.x;
  float o1 = (v.y - mean) * rstd * gv.y + bv.y;
  float o2 = (v.z - mean) * rstd * gv.z + bv.z;
  float o3 = (v.w - mean) * rstd * gv.w + bv.w;
  uint2 pk;
  pk.x = (unsigned int)f2bf(o0) | ((unsigned int)f2bf(o1) << 16);
  pk.y = (unsigned int)f2bf(o2) | ((unsigned int)f2bf(o3) << 16);
  *(uint2*)(out + (size_t)row * Dc + t * 4) = pk;
}

// ---------- bf16 MFMA GEMM: C[M,N] = A[M,K] @ Wt[N,K]^T, fused epilogue ----------
// flags: 1=+bias, 2=exact GELU, 4=+resid(fp32), 8=write bf16 to aux, 16=qkv split write
#define GBM 128
#define GBN 128
#define GBK 32

__global__ __launch_bounds__(256) void gemm_bf16(const unsigned short* __restrict__ A,
                                                 const unsigned short* __restrict__ Wt,
                                                 const float* __restrict__ bias,
                                                 const float* __restrict__ resid,
                                                 float* __restrict__ C,
                                                 unsigned short* __restrict__ aux,
                                                 int M, int N, int K, int flags) {
  __shared__ alignas(16) unsigned short As[GBM][GBK];   // 8 KB, row stride 64 B
  __shared__ alignas(16) unsigned short Bs[GBN][GBK];   // 8 KB (n-major)
  const int t = threadIdx.x;
  const int lane = t & 63, wave = t >> 6;
  const int wr = wave >> 1, wc = wave & 1;
  const int c = lane & 15, g = lane >> 4;
  const int row0 = blockIdx.y * GBM, col0 = blockIdx.x * GBN;

  f32x4 acc[4][4];
#pragma unroll
  for (int m = 0; m < 4; m++)
#pragma unroll
    for (int n = 0; n < 4; n++) acc[m][n] = (f32x4){0.f, 0.f, 0.f, 0.f};

  char* AsB = (char*)&As[0][0];
  char* BsB = (char*)&Bs[0][0];
  const int l0 = t, l1 = t + 256;
  const int lds0 = wave * 1024, lds1 = wave * 1024 + 4096;   // wave-uniform LDS bases

  for (int k0 = 0; k0 < K; k0 += GBK) {
    gload16(A + (size_t)(row0 + (l0 >> 2)) * K + k0 + (l0 & 3) * 8, AsB + lds0);
    gload16(A + (size_t)(row0 + (l1 >> 2)) * K + k0 + (l1 & 3) * 8, AsB + lds1);
    gload16(Wt + (size_t)(col0 + (l0 >> 2)) * K + k0 + (l0 & 3) * 8, BsB + lds0);
    gload16(Wt + (size_t)(col0 + (l1 >> 2)) * K + k0 + (l1 & 3) * 8, BsB + lds1);
    __syncthreads();
    bf16x8 af[4], bfv[4];
#pragma unroll
    for (int m = 0; m < 4; m++) af[m] = *(const bf16x8*)(AsB + (wr * 64 + m * 16 + c) * 64 + g * 16);
#pragma unroll
    for (int n = 0; n < 4; n++) bfv[n] = *(const bf16x8*)(BsB + (wc * 64 + n * 16 + c) * 64 + g * 16);
#pragma unroll
    for (int m = 0; m < 4; m++)
#pragma unroll
      for (int n = 0; n < 4; n++)
        acc[m][n] = __builtin_amdgcn_mfma_f32_16x16x32_bf16(af[m], bfv[n], acc[m][n], 0, 0, 0);
    __syncthreads();
  }

#pragma unroll
  for (int m = 0; m < 4; m++) {
    const int row = row0 + wr * 64 + m * 16 + g * 4;
#pragma unroll
    for (int n = 0; n < 4; n++) {
      const int col = col0 + wc * 64 + n * 16 + c;
      const float bi = (flags & 1) ? bias[col] : 0.0f;
#pragma unroll
      for (int r = 0; r < 4; r++) {
        float v = acc[m][n][r] + bi;
        if (flags & 2) v = 0.5f * v * (1.0f + erff(v * 0.70710678118654752f));
        if (flags & 4) v += resid[(size_t)(row + r) * N + col];
        if (flags & 16) {
          // qkv split: Q at 0, K at +4M, V (row-major) at +8M, all [bh][t][d] bf16
          int rr = row + r;
          int b = rr >> 11, tt = rr & 2047;
          int s = col >> 10, wcol = col & 1023;
          int h = wcol >> 6, f = wcol & 63;
          int bh = b * Hc + h;
          aux[(size_t)s * 4194304 + (size_t)bh * Tc * HDc + (size_t)tt * HDc + f] = f2bf(v);
        } else if (flags & 8) {
          aux[(size_t)(row + r) * N + col] = f2bf(v);
        } else {
          C[(size_t)(row + r) * N + col] = v;
        }
      }
    }
  }
}

// ---------- V transpose: V[bh][t][d] -> Vt[bh][d][t], 64x64 LDS tiles ----------
__global__ __launch_bounds__(256) void vtrans(const unsigned short* __restrict__ V,
                                              unsigned short* __restrict__ Vt) {
  __shared__ unsigned short tile[64][72];
  const int bh = blockIdx.y, t0 = blockIdx.x * 64;
  const int t = threadIdx.x;
  const int r8 = t >> 3, c8 = (t & 7) * 8;
#pragma unroll
  for (int p = 0; p < 2; p++) {
    int rr = p * 32 + r8;
    *(uint4*)&tile[rr][c8] = *(const uint4*)&V[((size_t)bh * Tc + t0 + rr) * HDc + c8];
  }
  __syncthreads();
#pragma unroll
  for (int p = 0; p < 2; p++) {
    int d = p * 32 + r8;
    unsigned short tmp[8];
#pragma unroll
    for (int j = 0; j < 8; j++) tmp[j] = tile[c8 + j][d];
    *(uint4*)&Vt[((size_t)bh * HDc + d) * Tc + t0 + c8] = *(uint4*)tmp;
  }
}

// ---------- MFMA flash attention v2: 64-key tiles, defer-max, swizzled P ----------
// Qb,Kb: [32 bh][2048][64] bf16 ; Vt: [32 bh][64][2048] bf16 ; Ob: [B][T][D] bf16
__global__ __launch_bounds__(256, 4) void fattn(const unsigned short* __restrict__ Qb,
                                                const unsigned short* __restrict__ Kb,
                                                const unsigned short* __restrict__ Vt,
                                                unsigned short* __restrict__ Ob) {
  __shared__ alignas(16) unsigned short P[4][16][64];   // 8 KB, 128 B rows, XOR-swizzled
  const int t = threadIdx.x, wave = t >> 6, lane = t & 63;
  const int c = lane & 15, g = lane >> 4;
  const int bid = blockIdx.x;
  const int bh = bid >> 5, qt = bid & 31;
  const int q0 = qt * 64 + wave * 16;

  const unsigned short* Qp = Qb + ((size_t)bh * Tc + q0) * HDc;
  const unsigned short* Kp = Kb + (size_t)bh * Tc * HDc;
  const unsigned short* Vp = Vt + (size_t)bh * HDc * Tc;
  char* Pw = (char*)&P[wave][0][0];

  const bf16x8 qf0 = *(const bf16x8*)(Qp + c * HDc + g * 8);
  const bf16x8 qf1 = *(const bf16x8*)(Qp + c * HDc + 32 + g * 8);

  const f32x4 z = {0.f, 0.f, 0.f, 0.f};
  f32x4 o[4] = {z, z, z, z};
  float m[4] = {-3e38f, -3e38f, -3e38f, -3e38f};   // running max, log2 domain
  float l[4] = {0.f, 0.f, 0.f, 0.f};
  float minm = -3e38f;
  const float Cs = 0.125f * 1.4426950408889634f;   // (1/sqrt(64)) * log2(e)

  for (int kt = 0; kt < Tc; kt += 64) {
    f32x4 s[4];
#pragma unroll
    for (int i = 0; i < 4; i++) {
      const bf16x8 k0 = *(const bf16x8*)(Kp + (size_t)(kt + i * 16 + c) * HDc + g * 8);
      const bf16x8 k1 = *(const bf16x8*)(Kp + (size_t)(kt + i * 16 + c) * HDc + 32 + g * 8);
      s[i] = __builtin_amdgcn_mfma_f32_16x16x32_bf16(qf0, k0, z, 0, 0, 0);
      s[i] = __builtin_amdgcn_mfma_f32_16x16x32_bf16(qf1, k1, s[i], 0, 0, 0);
    }
#pragma unroll
    for (int i = 0; i < 4; i++)
#pragma unroll
      for (int r = 0; r < 4; r++) s[i][r] *= Cs;

    float LM = s[0][0];
#pragma unroll
    for (int i = 0; i < 4; i++)
#pragma unroll
      for (int r = 0; r < 4; r++) LM = fmaxf(LM, s[i][r]);

    if (!__all(LM <= minm + 8.0f)) {               // rare rescale path (T13)
#pragma unroll
      for (int r = 0; r < 4; r++) {
        float rm = fmaxf(fmaxf(s[0][r], s[1][r]), fmaxf(s[2][r], s[3][r]));
        rm = fmaxf(rm, __shfl_xor(rm, 1));
        rm = fmaxf(rm, __shfl_xor(rm, 2));
        rm = fmaxf(rm, __shfl_xor(rm, 4));
        rm = fmaxf(rm, __shfl_xor(rm, 8));
        float nm = fmaxf(m[r], rm);
        float ef = exp2f(m[r] - nm);
        m[r] = nm;
        l[r] *= ef;
        o[0][r] *= ef; o[1][r] *= ef; o[2][r] *= ef; o[3][r] *= ef;
      }
      minm = fminf(fminf(m[0], m[1]), fminf(m[2], m[3]));
    }

#pragma unroll
    for (int r = 0; r < 4; r++) {
      const int rw = g * 4 + r;
      const int xr = ((rw & 7) << 4) ^ ((rw & 8) << 2);
      float p0 = exp2f(s[0][r] - m[r]);
      float p1 = exp2f(s[1][r] - m[r]);
      float p2 = exp2f(s[2][r] - m[r]);
      float p3 = exp2f(s[3][r] - m[r]);
      l[r] += (p0 + p1) + (p2 + p3);
      *(unsigned short*)(Pw + rw * 128 + ((c * 2) ^ xr))      = f2bf(p0);
      *(unsigned short*)(Pw + rw * 128 + ((32 + c * 2) ^ xr)) = f2bf(p1);
      *(unsigned short*)(Pw + rw * 128 + ((64 + c * 2) ^ xr)) = f2bf(p2);
      *(unsigned short*)(Pw + rw * 128 + ((96 + c * 2) ^ xr)) = f2bf(p3);
    }

    const int xc = ((c & 7) << 4) ^ ((c & 8) << 2);
    const bf16x8 pf0 = *(const bf16x8*)(Pw + c * 128 + ((g * 16) ^ xc));
    const bf16x8 pf1 = *(const bf16x8*)(Pw + c * 128 + ((64 + g * 16) ^ xc));
#pragma unroll
    for (int d4 = 0; d4 < 4; d4++) {
      const bf16x8 v0 = *(const bf16x8*)(Vp + (size_t)(d4 * 16 + c) * Tc + kt + g * 8);
      const bf16x8 v1 = *(const bf16x8*)(Vp + (size_t)(d4 * 16 + c) * Tc + kt + 32 + g * 8);
      o[d4] = __builtin_amdgcn_mfma_f32_16x16x32_bf16(pf0, v0, o[d4], 0, 0, 0);
      o[d4] = __builtin_amdgcn_mfma_f32_16x16x32_bf16(pf1, v1, o[d4], 0, 0, 0);
    }
  }

  float linv[4];
#pragma unroll
  for (int r = 0; r < 4; r++) {
    float L = l[r];
    L += __shfl_xor(L, 1); L += __shfl_xor(L, 2); L += __shfl_xor(L, 4); L += __shfl_xor(L, 8);
    linv[r] = 1.0f / L;
  }
  const int b = bh >> 4, h = bh & 15;
#pragma unroll
  for (int r = 0; r < 4; r++) {
    size_t rowoff = ((size_t)b * Tc + q0 + g * 4 + r) * Dc + h * HDc + c;
    Ob[rowoff + 0]  = f2bf(o[0][r] * linv[r]);
    Ob[rowoff + 16] = f2bf(o[1][r] * linv[r]);
    Ob[rowoff + 32] = f2bf(o[2][r] * linv[r]);
    Ob[rowoff + 48] = f2bf(o[3][r] * linv[r]);
  }
}

extern "C" void kernel_launch(void* const* d_in, const int* in_sizes, int n_in,
                              void* d_out, int out_size, void* d_ws, size_t ws_size,
                              hipStream_t stream) {
  const float* x     = (const float*)d_in[0];
  const float* w_qkv = (const float*)d_in[1];
  const float* w_out = (const float*)d_in[2];
  const float* w_ff1 = (const float*)d_in[3];
  const float* b_ff1 = (const float*)d_in[4];
  const float* w_ff2 = (const float*)d_in[5];
  const float* b_ff2 = (const float*)d_in[6];
  const float* g1    = (const float*)d_in[7];
  const float* be1   = (const float*)d_in[8];
  const float* g2    = (const float*)d_in[9];
  const float* be2   = (const float*)d_in[10];

  char* ws = (char*)d_ws;
  unsigned short* qkvb  = (unsigned short*)ws;                          // Q|K|V(row-major), 24 MB [0,24)
  unsigned short* xnvt  = (unsigned short*)(ws + ((size_t)24 << 20));   // xn (LN out) / Vt alias, 8 MB [24,32)
  unsigned short* Ob    = (unsigned short*)(ws + ((size_t)32 << 20));   // 8 MB  [32,40)
  unsigned short* hbuf  = (unsigned short*)(ws + ((size_t)40 << 20));   // 32 MB [40,72)
  unsigned short* wqkvT = (unsigned short*)(ws + ((size_t)72 << 20));   // 6 MB
  unsigned short* woutT = (unsigned short*)(ws + ((size_t)78 << 20));   // 2 MB
  unsigned short* wff1T = (unsigned short*)(ws + ((size_t)80 << 20));   // 8 MB
  unsigned short* wff2T = (unsigned short*)(ws + ((size_t)88 << 20));   // 8 MB -> 96 MB total
  float* x2 = (float*)d_out;   // fp32 residual scratch, overwritten by ff2 at the end

  dim3 blk(256);
  // weight transposes (fp32 -> bf16 [N][K])
  wconv_kernel<<<dim3(48, 16), blk, 0, stream>>>(w_qkv, wqkvT, Dc, 3 * Dc);
  wconv_kernel<<<dim3(16, 16), blk, 0, stream>>>(w_out, woutT, Dc, Dc);
  wconv_kernel<<<dim3(64, 16), blk, 0, stream>>>(w_ff1, wff1T, Dc, 4 * Dc);
  wconv_kernel<<<dim3(16, 64), blk, 0, stream>>>(w_ff2, wff2T, 4 * Dc, Dc);

  // xn = LN(x) in bf16   (xn lives in the xn/Vt alias region)
  ln_kernel<<<Mc, blk, 0, stream>>>(x, g1, be1, xnvt);
  // qkv GEMM with split Q/K/V bf16 epilogue
  gemm_bf16<<<dim3(24, 32), blk, 0, stream>>>(xnvt, wqkvT, nullptr, nullptr, nullptr, qkvb,
                                              Mc, 3 * Dc, Dc, 16);
  // V transpose into the (now dead) xn region
  vtrans<<<dim3(32, 32), blk, 0, stream>>>(qkvb + 8388608, xnvt);
  // flash attention
  fattn<<<dim3(1024), blk, 0, stream>>>(qkvb, qkvb + 4194304, xnvt, Ob);
  // x2 = x + attn @ w_out   (fp32 into d_out)
  gemm_bf16<<<dim3(8, 32), blk, 0, stream>>>(Ob, woutT, nullptr, x, x2, nullptr,
                                             Mc, Dc, Dc, 4);
  // xn = LN(x2) in bf16  (fattn done; region reusable)
  ln_kernel<<<Mc, blk, 0, stream>>>(x2, g2, be2, xnvt);
  // h = gelu(xn @ w_ff1 + b1) in bf16
  gemm_bf16<<<dim3(32, 32), blk, 0, stream>>>(xnvt, wff1T, b_ff1, nullptr, nullptr, hbuf,
                                              Mc, 4 * Dc, Dc, 1 | 2 | 8);
  // out = x2 + h @ w_ff2 + b2  (fp32)
  gemm_bf16<<<dim3(8, 32), blk, 0, stream>>>(hbuf, wff2T, b_ff2, x2, (float*)d_out, nullptr,
                                             Mc, Dc, 4 * Dc, 1 | 4);
}